// Round 5
// baseline (269.834 us; speedup 1.0000x reference)
//
#include <hip/hip_runtime.h>
#include <stdint.h>

#define N_ANCH 102400
#define FMP 320
#define K_TOP 1000
#define NMS_T 0.6f
#define SC_CLAMP 6.907755278982137f
#define IMGF 1280.0f
#define NBINS 16384   // scores in (0,1) => float bits>>16 < 0x4000

// ---- workspace layout (bytes) ----
#define OFF_SCORES   0u          // f32[102400]
#define OFF_LABELS   409600u     // u32[102400]
#define OFF_HIST     819200u     // u32[16384]
#define OFF_META     884736u     // u32[64]: [0]=cutoff [2]=cand ctr [8]=hist arrive [9]=collect arrive [10]=mask arrive
#define OFF_KEYS     884992u     // u64[4096]
#define OFF_BOXES    917760u     // f32[4000]
#define OFF_LAB1K    933760u     // u32[1000]
#define OFF_MASK     937760u     // u64[16000]
#define OFF_DIAG     1065760u    // u64[1024]  diag[i] = word (i>>6) of mask row i

__device__ __forceinline__ float sigf(float x) {
    return 1.0f / (1.0f + expf(-x));
}

// ---------------- K1: scores+argmax, fused ws zeroing ----------------
// 1600 blocks x 256. Blocks 0..63 zero hist; block 64 zeros meta+diag.
__global__ __launch_bounds__(256) void k_scores(const float* __restrict__ hmp,
                                                const float* __restrict__ iou,
                                                float* __restrict__ scores,
                                                uint32_t* __restrict__ labels,
                                                uint32_t* __restrict__ hist,
                                                uint32_t* __restrict__ meta,
                                                uint64_t* __restrict__ diag) {
    int blk = blockIdx.x;
    if (blk < 64) {
        hist[blk * 256 + threadIdx.x] = 0u;
    } else if (blk == 64) {
        if (threadIdx.x < 64) meta[threadIdx.x] = 0u;
#pragma unroll
        for (int k = 0; k < 4; ++k) diag[threadIdx.x * 4 + k] = 0ull;
    }
    int gid = blk * 256 + threadIdx.x;
    int a = gid >> 2;
    int q = gid & 3;
    float si = sigf(iou[a]);
    const float4* row4 = (const float4*)hmp + (size_t)a * 20 + q;
    float4 v[5];
#pragma unroll
    for (int j = 0; j < 5; ++j) v[j] = row4[j * 4];
    float best = -1.0f;
    int bc = 0;
#pragma unroll
    for (int j = 0; j < 5; ++j) {
        int cb = j * 16 + q * 4;
        float f;
        f = sqrtf(sigf(v[j].x) * si); if (f > best) { best = f; bc = cb; }
        f = sqrtf(sigf(v[j].y) * si); if (f > best) { best = f; bc = cb + 1; }
        f = sqrtf(sigf(v[j].z) * si); if (f > best) { best = f; bc = cb + 2; }
        f = sqrtf(sigf(v[j].w) * si); if (f > best) { best = f; bc = cb + 3; }
    }
#pragma unroll
    for (int off = 1; off <= 2; off <<= 1) {
        float of = __shfl_xor(best, off);
        int   oc = __shfl_xor(bc, off);
        if (of > best || (of == best && oc < bc)) { best = of; bc = oc; }
    }
    if (q == 0) {
        scores[a] = best;
        labels[a] = (uint32_t)bc;
    }
}

// ---------------- K2: LDS-private histogram; last block finds cutoff ----------------
__global__ __launch_bounds__(1024) void k_hist(const float* __restrict__ scores,
                                               uint32_t* __restrict__ hist,
                                               uint32_t* __restrict__ meta) {
    __shared__ uint32_t lh[NBINS];
    __shared__ int lastFlag;
    for (int i = threadIdx.x; i < NBINS; i += 1024) lh[i] = 0u;
    __syncthreads();
    int base = blockIdx.x * 1600;
    for (int k = threadIdx.x; k < 1600; k += 1024) {
        uint32_t bin = __float_as_uint(scores[base + k]) >> 16;
        atomicAdd(&lh[bin], 1u);
    }
    __syncthreads();
    for (int i = threadIdx.x; i < NBINS; i += 1024) {
        uint32_t c = lh[i];
        if (c) atomicAdd(&hist[i], c);
    }
    __threadfence();
    __syncthreads();
    if (threadIdx.x == 0) lastFlag = (atomicAdd(&meta[8], 1u) == 63u);
    __syncthreads();
    if (!lastFlag) return;
    __threadfence();
    // ---- cutoff: largest bin B with count(bin >= B) >= K_TOP ----
    int t = threadIdx.x;
    uint32_t s = 0;
#pragma unroll
    for (int b = 0; b < 16; ++b) s += hist[t * 16 + b];
    lh[t] = s;                       // reuse lh[0..1023] as suffix-sum buffer
    __syncthreads();
    for (int off = 1; off < 1024; off <<= 1) {
        uint32_t v = lh[t] + ((t + off < 1024) ? lh[t + off] : 0u);
        __syncthreads();
        lh[t] = v;
        __syncthreads();
    }
    uint32_t inc   = lh[t];
    uint32_t above = (t < 1023) ? lh[t + 1] : 0u;
    if (above < K_TOP && inc >= K_TOP) {
        uint32_t loc[16];
#pragma unroll
        for (int b = 0; b < 16; ++b) loc[b] = hist[t * 16 + b];
        uint32_t cnt = above;
        for (int b = 15; b >= 0; --b) {
            cnt += loc[b];
            if (cnt >= K_TOP) { meta[0] = (uint32_t)(t * 16 + b); break; }
        }
    }
}

// ---------------- K3: collect candidates; last block ranks + decodes ----------------
// 100 blocks x 1024 = 102400 threads exactly.
__global__ __launch_bounds__(1024) void k_collect(const float* __restrict__ scores,
                                                  uint32_t* __restrict__ meta,
                                                  uint64_t* __restrict__ keys,
                                                  const uint32_t* __restrict__ labels,
                                                  const float* __restrict__ reg,
                                                  float* __restrict__ out,
                                                  float* __restrict__ boxes,
                                                  uint32_t* __restrict__ lab1k) {
    __shared__ uint64_t sk[4096];
    __shared__ int lastFlag;
    int i = blockIdx.x * 1024 + threadIdx.x;
    uint32_t bits = __float_as_uint(scores[i]);
    if ((bits >> 16) >= meta[0]) {
        uint32_t pos = atomicAdd(&meta[2], 1u);
        if (pos < 4096)
            keys[pos] = ((uint64_t)bits << 32) | (uint64_t)(0xFFFFFFFFu - (uint32_t)i);
    }
    __threadfence();
    __syncthreads();
    if (threadIdx.x == 0) lastFlag = (atomicAdd(&meta[9], 1u) == 99u);
    __syncthreads();
    if (!lastFlag) return;
    __threadfence();
    uint32_t M = meta[2];
    if (M > 4096u) M = 4096u;
    for (uint32_t k = threadIdx.x; k < M; k += 1024) sk[k] = keys[k];
    __syncthreads();
    for (uint32_t c = threadIdx.x; c < M; c += 1024) {
        uint64_t mykey = sk[c];
        uint32_t rank = 0;
        uint32_t j = 0;
        for (; j + 8 <= M; j += 8) {
#pragma unroll
            for (int u = 0; u < 8; ++u) rank += (sk[j + u] > mykey) ? 1u : 0u;
        }
        for (; j < M; ++j) rank += (sk[j] > mykey) ? 1u : 0u;
        if (rank >= K_TOP) continue;
        int t = (int)rank;
        uint32_t sbits = (uint32_t)(mykey >> 32);
        uint32_t idx   = 0xFFFFFFFFu - (uint32_t)(mykey & 0xFFFFFFFFull);
        float score = __uint_as_float(sbits);
        uint32_t lab = labels[idx];
        out[t]         = score;
        out[K_TOP + t] = (float)lab;
        lab1k[t]       = lab;
        float ax = (float)(idx % FMP);
        float ay = (float)(idx / FMP);
        float4 rr = ((const float4*)reg)[idx];
        float e0 = expf(fminf(rr.x, SC_CLAMP));
        float e1 = expf(fminf(rr.y, SC_CLAMP));
        float e2 = expf(fminf(rr.z, SC_CLAMP));
        float e3 = expf(fminf(rr.w, SC_CLAMP));
        float x1 = fminf(fmaxf((ax - e0) * 4.0f / IMGF, 0.0f), 1.0f);
        float y1 = fminf(fmaxf((ay - e1) * 4.0f / IMGF, 0.0f), 1.0f);
        float x2 = fminf(fmaxf((ax + e2) * 4.0f / IMGF, 0.0f), 1.0f);
        float y2 = fminf(fmaxf((ay + e3) * 4.0f / IMGF, 0.0f), 1.0f);
        out[2 * K_TOP + t * 4 + 0] = x1;
        out[2 * K_TOP + t * 4 + 1] = y1;
        out[2 * K_TOP + t * 4 + 2] = x2;
        out[2 * K_TOP + t * 4 + 3] = y2;
        boxes[t * 4 + 0] = x1;
        boxes[t * 4 + 1] = y1;
        boxes[t * 4 + 2] = x2;
        boxes[t * 4 + 3] = y2;
    }
}

// ---------------- K4: suppress masks; last block's wave 0 runs greedy scan ----------------
__global__ __launch_bounds__(256) void k_mask(const float* __restrict__ boxes,
                                              const uint32_t* __restrict__ lab1k,
                                              uint64_t* __restrict__ mask,
                                              uint64_t* __restrict__ diag,
                                              uint32_t* __restrict__ meta,
                                              float* __restrict__ out) {
    __shared__ int lastFlag;
    int i = blockIdx.x;
    int lane = threadIdx.x & 63;
    int wv = threadIdx.x >> 6;
    float4 bi = ((const float4*)boxes)[i];
    uint32_t li = lab1k[i];
    float areai = (bi.z - bi.x) * (bi.w - bi.y);
    int iw = i >> 6;   // diagonal word of row i
#pragma unroll
    for (int w0 = 0; w0 < 4; ++w0) {
        int w = wv + w0 * 4;
        int j = w * 64 + lane;
        bool sup = false;
        if (j < K_TOP && j > i) {
            float4 bj = ((const float4*)boxes)[j];
            float areaj = (bj.z - bj.x) * (bj.w - bj.y);
            float xx1 = fmaxf(bi.x, bj.x);
            float yy1 = fmaxf(bi.y, bj.y);
            float xx2 = fminf(bi.z, bj.z);
            float yy2 = fminf(bi.w, bj.w);
            float ww = fmaxf(1e-10f, xx2 - xx1);
            float hh = fmaxf(1e-10f, yy2 - yy1);
            float inter = ww * hh;
            float iouv = inter / (areai + areaj - inter + 1e-10f);
            sup = (iouv > NMS_T) && (li == lab1k[j]);
        }
        unsigned long long m = __ballot(sup);
        if (lane == 0) {
            mask[(size_t)i * 16 + w] = (uint64_t)m;
            if (w == iw) diag[i] = (uint64_t)m;
        }
    }
    __threadfence();
    __syncthreads();
    if (threadIdx.x == 0) lastFlag = (atomicAdd(&meta[10], 1u) == (uint32_t)(K_TOP - 1));
    __syncthreads();
    if (!lastFlag || threadIdx.x >= 64) return;
    __threadfence();
    // ---- greedy scan, wave 0 ----
    // lane l: q = l>>4 (row subgroup mod 4), w = l&15 (word). remv per lane:
    // OR of word w over kept rows == q (mod 4). keep falls out as ~D (mask is
    // strictly upper-triangular, so bit b of D is final by step b).
    int q = lane >> 4, wrd = lane & 15;
    uint64_t remv = 0ull;
    uint64_t dcur = diag[lane];
    for (int g = 0; g < 16; ++g) {
        uint64_t dnxt = (g < 15) ? diag[64 * (g + 1) + lane] : 0ull;
        uint64_t bun[16];
        if (g < 15) {
#pragma unroll
            for (int r4 = 0; r4 < 16; ++r4)
                bun[r4] = mask[(size_t)(64 * g + 4 * r4 + q) * 16 + wrd];
        }
        // D init = word g of remv: merge lanes {g, 16+g, 32+g, 48+g}
        uint32_t dlo = 0, dhi = 0;
#pragma unroll
        for (int qq = 0; qq < 4; ++qq) {
            dlo |= __builtin_amdgcn_readlane((uint32_t)remv, qq * 16 + g);
            dhi |= __builtin_amdgcn_readlane((uint32_t)(remv >> 32), qq * 16 + g);
        }
        uint64_t D = ((uint64_t)dhi << 32) | dlo;
        // serial chain: 64 rows, branchless scalar ops
#pragma unroll
        for (int b = 0; b < 64; ++b) {
            uint32_t tlo = __builtin_amdgcn_readlane((uint32_t)dcur, b);
            uint32_t thi = __builtin_amdgcn_readlane((uint32_t)(dcur >> 32), b);
            uint64_t T = ((uint64_t)thi << 32) | tlo;
            uint64_t sel = ((D >> b) & 1ull) - 1ull;   // ~0 if row kept
            D |= T & sel;
        }
        uint64_t keepg = ~D;
        int j = g * 64 + lane;
        if (j < K_TOP) out[6 * K_TOP + j] = (float)((keepg >> lane) & 1ull);
        if (g < 15) {
#pragma unroll
            for (int r4 = 0; r4 < 16; ++r4) {
                uint32_t kb = (uint32_t)(keepg >> (4 * r4 + q)) & 1u;
                uint64_t mm = 0ull - (uint64_t)kb;
                remv |= bun[r4] & mm;
            }
        }
        dcur = dnxt;
    }
}

extern "C" void kernel_launch(void* const* d_in, const int* in_sizes, int n_in,
                              void* d_out, int out_size, void* d_ws, size_t ws_size,
                              hipStream_t stream) {
    const float* hmp = (const float*)d_in[0];
    const float* reg = (const float*)d_in[1];
    const float* iou = (const float*)d_in[2];
    float* out = (float*)d_out;
    char* ws = (char*)d_ws;

    float*    scores = (float*)(ws + OFF_SCORES);
    uint32_t* labels = (uint32_t*)(ws + OFF_LABELS);
    uint32_t* hist   = (uint32_t*)(ws + OFF_HIST);
    uint32_t* meta   = (uint32_t*)(ws + OFF_META);
    uint64_t* keys   = (uint64_t*)(ws + OFF_KEYS);
    float*    boxes  = (float*)(ws + OFF_BOXES);
    uint32_t* lab1k  = (uint32_t*)(ws + OFF_LAB1K);
    uint64_t* mask   = (uint64_t*)(ws + OFF_MASK);
    uint64_t* diag   = (uint64_t*)(ws + OFF_DIAG);

    k_scores<<<dim3(N_ANCH * 4 / 256), dim3(256), 0, stream>>>(hmp, iou, scores, labels, hist, meta, diag);
    k_hist<<<dim3(64), dim3(1024), 0, stream>>>(scores, hist, meta);
    k_collect<<<dim3(100), dim3(1024), 0, stream>>>(scores, meta, keys, labels, reg, out, boxes, lab1k);
    k_mask<<<dim3(K_TOP), dim3(256), 0, stream>>>(boxes, lab1k, mask, diag, meta, out);
}